// Round 13
// baseline (237.210 us; speedup 1.0000x reference)
//
#include <hip/hip_runtime.h>

typedef _Float16 f16;
typedef _Float16 f16x8 __attribute__((ext_vector_type(8)));
typedef float f32x4 __attribute__((ext_vector_type(4)));
typedef uint32_t u32x4 __attribute__((ext_vector_type(4)));

#define NBLK 8
#define NS 3  // independent 16-point streams per wave
#define MFMA(a, b, c) __builtin_amdgcn_mfma_f32_16x16x32_f16(a, b, c, 0, 0, 0)
#define LOG2E 1.4426950408889634f

// Consumer-side K position k -> producer-side slot feature index.
__device__ __forceinline__ int pinv(int k) {
  return 16 * (2 * (k >> 5) + ((k >> 2) & 1)) + 4 * ((k >> 3) & 3) + (k & 3);
}
__device__ __forceinline__ float hi_part(float v) { return (float)(f16)v; }
__device__ __forceinline__ float lo_part(float v) { f16 h = (f16)v; return v - (float)h; }

__device__ __forceinline__ float fast_exp2(float x) {
  float r; asm("v_exp_f32 %0, %1" : "=v"(r) : "v"(x)); return r;
}
__device__ __forceinline__ float fast_rcp(float x) {
  float r; asm("v_rcp_f32 %0, %1" : "=v"(r) : "v"(x)); return r;
}
__device__ __forceinline__ uint32_t pkrtz_u(float a, float b) {
  auto p = __builtin_amdgcn_cvt_pkrtz(a, b);
  return __builtin_bit_cast(uint32_t, p);
}
// Packed lo-residual for the x-state split (used in B1 only).
__device__ __forceinline__ uint32_t mix_lo_pk(uint32_t hi_pk, float neg1,
                                              float r0, float r1) {
  uint32_t d;
  asm("v_fma_mixlo_f16 %0, %1, %2, %3 op_sel:[0,0,0] op_sel_hi:[1,0,0]\n\t"
      "v_fma_mixhi_f16 %0, %1, %2, %4 op_sel:[1,0,0] op_sel_hi:[1,0,0]"
      : "=&v"(d)
      : "v"(hi_pk), "v"(neg1), "v"(r0), "v"(r1));
  return d;
}

// One-time prep: fragment-layout f16 weight images + folded couple constants.
// Per block i (img 0..23, 512 f16 each):
//   img 0..3   A1[t]   (K: 0-3 W1hi, 4-7 W1lo, 8-11 W1hi, 12/13 b1 hi/lo)
//   img 4..11  A2hi[t*2+s], img 12..19 A2lo[t*2+s]
//   img 20,21  A3hi[s],     img 22,23  A3lo[s]  (W3 rows pre-scaled AND
//     replicated into every 4-row group so every lane gets a0..a3 in d3)
// img 24: couple constants (cwp): per block i, 24 floats:
//   [0..15] Wp'=Wp*diag(sc), [16..19] pb=Wp*go, [20..23] b3 pre-scaled;
//   cwp[192] = grand sum of log(scale).
__global__ void prep_weights(const float* __restrict__ W1, const float* __restrict__ b1,
                             const float* __restrict__ W2, const float* __restrict__ W3,
                             const float* __restrict__ b3, const float* __restrict__ w_perm,
                             const float* __restrict__ g_scale, const float* __restrict__ g_offset,
                             f16* __restrict__ wsp, float* __restrict__ cwp) {
  int i = blockIdx.x / 25;
  int img = blockIdx.x % 25;
  if (img == 24) {
    int tid = threadIdx.x;
    if (tid < 16) {
      int cc = tid & 3;
      float gs = g_scale[i * 4 + cc];
      float sc = 0.2f * log1pf(expf(0.5f * gs));
      cwp[i * 24 + tid] = w_perm[i * 16 + tid] * sc;
    } else if (tid < 20) {
      int r = tid - 16;
      float acc = 0.f;
      for (int cc = 0; cc < 4; ++cc)
        acc += w_perm[i * 16 + r * 4 + cc] * g_offset[i * 4 + cc];
      cwp[i * 24 + 16 + r] = acc;
    } else if (tid < 24) {
      int j = tid - 20;
      float scale = (j < 2) ? (0.2f * LOG2E) : 0.1f;
      cwp[i * 24 + 20 + j] = b3[i * 4 + j] * scale;
    } else if (tid == 24 && i == 0) {
      float acc = 0.f;
      for (int k = 0; k < 32; ++k)
        acc += logf(0.2f * log1pf(expf(0.5f * g_scale[k])));
      cwp[192] = acc;
    }
    return;
  }
  int lane = threadIdx.x;
  int c = lane & 15, g = lane >> 4;
  f16 vals[8];
#pragma unroll
  for (int e = 0; e < 8; ++e) {
    float out = 0.f;
    if (img < 4) {
      int t = img, m = 16 * t + c, k = 8 * g + e;
      if (k < 4)        out = hi_part(W1[i * 256 + m * 4 + k]);
      else if (k < 8)   out = lo_part(W1[i * 256 + m * 4 + (k - 4)]);
      else if (k < 12)  out = hi_part(W1[i * 256 + m * 4 + (k - 8)]);
      else if (k == 12) out = hi_part(b1[i * 64 + m]);
      else if (k == 13) out = lo_part(b1[i * 64 + m]);
      else out = 0.f;
    } else if (img < 20) {
      bool isLo = (img >= 12);
      int q = isLo ? (img - 12) : (img - 4);
      int t = q >> 1, s = q & 1, m = 16 * t + c;
      int k = 32 * s + 8 * g + e;
      float v = W2[i * 4096 + m * 64 + pinv(k)];
      out = isLo ? lo_part(v) : hi_part(v);
    } else {
      bool isLo = (img >= 22);
      int s = isLo ? (img - 22) : (img - 20);
      int k = 32 * s + 8 * g + e;
      int rr = c & 3;  // replicate W3 rows into every 4-row group
      float rs = (rr < 2) ? (0.2f * LOG2E) : 0.1f;  // fold 0.1 and 2*log2e
      float v = W3[i * 256 + rr * 64 + pinv(k)] * rs;
      out = isLo ? lo_part(v) : hi_part(v);
    }
    vals[e] = (f16)out;
  }
  f16x8 vv = {vals[0], vals[1], vals[2], vals[3], vals[4], vals[5], vals[6], vals[7]};
  *(f16x8*)(wsp + ((size_t)i * 24 + img) * 512 + (size_t)lane * 8) = vv;
}

// Two D tiles -> packed RTZ f16 conversion + packed relu: 8 VALU ops total
// (was ~20 with scalar cvt). relu-after-convert == convert-after-relu here.
__device__ __forceinline__ f16x8 make_bh(const f32x4 d0, const f32x4 d1,
                                         uint32_t zero_u) {
  u32x4 u;
  u[0] = pkrtz_u(d0[0], d0[1]);
  u[1] = pkrtz_u(d0[2], d0[3]);
  u[2] = pkrtz_u(d1[0], d1[1]);
  u[3] = pkrtz_u(d1[2], d1[3]);
#pragma unroll
  for (int p = 0; p < 4; ++p) {
    uint32_t r;
    asm("v_pk_max_f16 %0, %1, %2" : "=v"(r) : "v"(u[p]), "v"(zero_u));
    u[p] = r;
  }
  return __builtin_bit_cast(f16x8, u);
}

struct Pt {
  float x0, x1, x2, x3, ld;
  uint32_t ch_pk, cl_pk;
};

__device__ __forceinline__ f16x8 build_B1(const Pt& s, bool g0, bool g1, float neg1) {
  const uint32_t ones_pk = 0x3C003C00u;  // packed f16 {1,1}
  uint32_t xh_pk = pkrtz_u(s.x0, s.x1);
  uint32_t xl_pk = mix_lo_pk(xh_pk, neg1, s.x0, s.x1);
  u32x4 B1u = {g0 ? xh_pk : (g1 ? xl_pk : 0u),
               g0 ? s.ch_pk : (g1 ? s.cl_pk : 0u),
               g0 ? xh_pk : (g1 ? ones_pk : 0u),
               g0 ? s.ch_pk : 0u};
  return __builtin_bit_cast(f16x8, B1u);
}

// d3 regs (ALL lanes, via W3 row-replication): 0,1 = 2a*log2e ; 2,3 = t.
__device__ __forceinline__ void couple(Pt& st, const f32x4 d3,
                                       const float* __restrict__ cw) {
  float a0 = d3[0] + cw[20];
  float a1 = d3[1] + cw[21];
  float t2 = d3[2] + cw[22];
  float t3 = d3[3] + cw[23];
  float u0 = fast_exp2(a0), u1 = fast_exp2(a1);          // e^{2a}
  float s0 = fmaf(-4.f, fast_rcp(u0 + 1.f), 2.f);        // 2*tanh(a)
  float s1 = fmaf(-4.f, fast_rcp(u1 + 1.f), 2.f);
  float e0 = fast_exp2(s0 * LOG2E), e1 = fast_exp2(s1 * LOG2E);
  st.x2 = fmaf(st.x2, e0, t2);
  st.x3 = fmaf(st.x3, e1, t3);
  st.ld += s0 + s1;
  // fused actnorm+permutation: nx_r = pb[r] + sum_c Wp'[r][c]*x_c
  float nx0 = fmaf(st.x0, cw[0],  fmaf(st.x1, cw[1],  fmaf(st.x2, cw[2],  fmaf(st.x3, cw[3],  cw[16]))));
  float nx1 = fmaf(st.x0, cw[4],  fmaf(st.x1, cw[5],  fmaf(st.x2, cw[6],  fmaf(st.x3, cw[7],  cw[17]))));
  float nx2 = fmaf(st.x0, cw[8],  fmaf(st.x1, cw[9],  fmaf(st.x2, cw[10], fmaf(st.x3, cw[11], cw[18]))));
  float nx3 = fmaf(st.x0, cw[12], fmaf(st.x1, cw[13], fmaf(st.x2, cw[14], fmaf(st.x3, cw[15], cw[19]))));
  st.x0 = nx0; st.x1 = nx1; st.x2 = nx2; st.x3 = nx3;
}

// Triple-stream, f16 activations, split weights, SPLIT accumulator chains:
// L2/L3 hi- and lo-weight products accumulate in independent chains (depth 2
// instead of 4) and are summed with one packed f32 add — 6 independent MFMA
// chains interleave at the chain-stall points instead of 3.
__global__ __launch_bounds__(256) void cinn_mfma_kernel(
    const float* __restrict__ q_feat, const float* __restrict__ Hc,
    const float* __restrict__ b2, const f16* __restrict__ wf,
    const float* __restrict__ cwp,
    float* __restrict__ out_x, float* __restrict__ out_ld, int n) {
  int lane = threadIdx.x & 63;
  int c = lane & 15, g = lane >> 4;
  bool g0 = (g == 0), g1 = (g == 1);
  int wave = (blockIdx.x * blockDim.x + threadIdx.x) >> 6;
  float neg1 = -1.0f;
  uint32_t zero_u = 0u;

  int pt[NS];
  Pt st[NS];
#pragma unroll
  for (int u = 0; u < NS; ++u) {
    int p = wave * (16 * NS) + u * 16 + c;
    if (p >= n) p = n - 1;  // clamped lanes compute identical results (benign)
    pt[u] = p;
    float4 xv = *reinterpret_cast<const float4*>(q_feat + (size_t)p * 4);
    st[u].x0 = xv.x; st[u].x1 = xv.y; st[u].x2 = xv.z; st[u].x3 = xv.w;
    st[u].ld = 0.f;
    float2 hv = *reinterpret_cast<const float2*>(Hc + (size_t)p * 2);
    st[u].ch_pk = pkrtz_u(hv.x, hv.y);
    st[u].cl_pk = mix_lo_pk(st[u].ch_pk, neg1, hv.x, hv.y);
  }

  const f32x4 zero4 = {0.f, 0.f, 0.f, 0.f};

#pragma unroll 1
  for (int i = 0; i < NBLK; ++i) {
    const f16* wb = wf + (size_t)i * 24 * 512 + (size_t)lane * 8;
    const float* cw = cwp + i * 24;

    f16x8 B1[NS];
#pragma unroll
    for (int u = 0; u < NS; ++u) B1[u] = build_B1(st[u], g0, g1, neg1);

    // L1 (split terms + b1 folded into K-slots)
    f16x8 b2h[NS][2];
#pragma unroll
    for (int half = 0; half < 2; ++half) {
      f32x4 dp[NS][2];
#pragma unroll
      for (int tt = 0; tt < 2; ++tt) {
        f16x8 a = *(const f16x8*)(wb + (2 * half + tt) * 512);
#pragma unroll
        for (int u = 0; u < NS; ++u) dp[u][tt] = MFMA(a, B1[u], zero4);
      }
#pragma unroll
      for (int u = 0; u < NS; ++u)
        b2h[u][half] = make_bh(dp[u][0], dp[u][1], zero_u);
    }

    // L2: Whi*h and Wlo*h in SEPARATE chains (depth 2), packed-add at end.
    f16x8 b3h[NS][2];
#pragma unroll
    for (int half = 0; half < 2; ++half) {
      f32x4 d2[NS][2];
#pragma unroll
      for (int tt = 0; tt < 2; ++tt) {
        int t = 2 * half + tt;
        f16x8 ah0 = *(const f16x8*)(wb + (4 + 2 * t + 0) * 512);
        f16x8 ah1 = *(const f16x8*)(wb + (4 + 2 * t + 1) * 512);
        f16x8 al0 = *(const f16x8*)(wb + (12 + 2 * t + 0) * 512);
        f16x8 al1 = *(const f16x8*)(wb + (12 + 2 * t + 1) * 512);
        const float4 bv = *reinterpret_cast<const float4*>(b2 + i * 64 + 16 * t + 4 * g);
        f32x4 cin = {bv.x, bv.y, bv.z, bv.w};
#pragma unroll
        for (int u = 0; u < NS; ++u) {
          f32x4 acch = MFMA(ah0, b2h[u][0], cin);
          acch = MFMA(ah1, b2h[u][1], acch);
          f32x4 accl = MFMA(al0, b2h[u][0], zero4);
          accl = MFMA(al1, b2h[u][1], accl);
          d2[u][tt] = acch + accl;
        }
      }
#pragma unroll
      for (int u = 0; u < NS; ++u)
        b3h[u][half] = make_bh(d2[u][0], d2[u][1], zero_u);
    }

    // L3: split chains; rows replicated -> every lane gets a0..a3
    f32x4 d3[NS];
    {
      f16x8 ah0 = *(const f16x8*)(wb + 20 * 512);
      f16x8 ah1 = *(const f16x8*)(wb + 21 * 512);
      f16x8 al0 = *(const f16x8*)(wb + 22 * 512);
      f16x8 al1 = *(const f16x8*)(wb + 23 * 512);
#pragma unroll
      for (int u = 0; u < NS; ++u) {
        f32x4 acch = MFMA(ah0, b3h[u][0], zero4);
        acch = MFMA(ah1, b3h[u][1], acch);
        f32x4 accl = MFMA(al0, b3h[u][0], zero4);
        accl = MFMA(al1, b3h[u][1], accl);
        d3[u] = acch + accl;
      }
    }

#pragma unroll
    for (int u = 0; u < NS; ++u) couple(st[u], d3[u], cw);
  }

  if (lane < 16) {
    float lt = cwp[192];
#pragma unroll
    for (int u = 0; u < NS; ++u) {
      *reinterpret_cast<float4*>(out_x + (size_t)pt[u] * 4) =
          make_float4(st[u].x0, st[u].x1, st[u].x2, st[u].x3);
      out_ld[pt[u]] = st[u].ld + lt;
    }
  }
}

extern "C" void kernel_launch(void* const* d_in, const int* in_sizes, int n_in,
                              void* d_out, int out_size, void* d_ws, size_t ws_size,
                              hipStream_t stream) {
  const float* q_feat   = (const float*)d_in[0];
  const float* Hc       = (const float*)d_in[1];
  const float* W1       = (const float*)d_in[2];
  const float* b1       = (const float*)d_in[3];
  const float* W2       = (const float*)d_in[4];
  const float* b2       = (const float*)d_in[5];
  const float* W3       = (const float*)d_in[6];
  const float* b3       = (const float*)d_in[7];
  const float* w_perm   = (const float*)d_in[8];
  const float* g_scale  = (const float*)d_in[9];
  const float* g_offset = (const float*)d_in[10];

  int n = in_sizes[0] / 4;
  float* out_x  = (float*)d_out;
  float* out_ld = out_x + (size_t)n * 4;
  f16* wf = (f16*)d_ws;                        // 8*24*512*2 = 196608 B
  float* cwp = (float*)((char*)d_ws + 196608); // 193 floats

  hipLaunchKernelGGL(prep_weights, dim3(NBLK * 25), dim3(64), 0, stream,
                     W1, b1, W2, W3, b3, w_perm, g_scale, g_offset, wf, cwp);
  int ppb = 256 / 64 * 16 * NS;  // points per 256-thread block = 192
  int blocks = (n + ppb - 1) / ppb;
  hipLaunchKernelGGL(cinn_mfma_kernel, dim3(blocks), dim3(256), 0, stream,
                     q_feat, Hc, b2, wf, cwp, out_x, out_ld, n);
}

// Round 14
// 161.050 us; speedup vs baseline: 1.4729x; 1.4729x over previous
//
#include <hip/hip_runtime.h>

typedef _Float16 f16;
typedef _Float16 f16x8 __attribute__((ext_vector_type(8)));
typedef float f32x4 __attribute__((ext_vector_type(4)));
typedef uint32_t u32x4 __attribute__((ext_vector_type(4)));

#define NBLK 8
#define NS 3  // independent 16-point streams per wave
#define NIMG 14
#define MFMA(a, b, c) __builtin_amdgcn_mfma_f32_16x16x32_f16(a, b, c, 0, 0, 0)
#define LOG2E 1.4426950408889634f

// Consumer-side K position k -> producer-side slot feature index.
__device__ __forceinline__ int pinv(int k) {
  return 16 * (2 * (k >> 5) + ((k >> 2) & 1)) + 4 * ((k >> 3) & 3) + (k & 3);
}
__device__ __forceinline__ float hi_part(float v) { return (float)(f16)v; }  // RNE
__device__ __forceinline__ float lo_part(float v) { f16 h = (f16)v; return v - (float)h; }

__device__ __forceinline__ float fast_exp2(float x) {
  float r; asm("v_exp_f32 %0, %1" : "=v"(r) : "v"(x)); return r;
}
__device__ __forceinline__ float fast_rcp(float x) {
  float r; asm("v_rcp_f32 %0, %1" : "=v"(r) : "v"(x)); return r;
}
__device__ __forceinline__ uint32_t pkrtz_u(float a, float b) {
  auto p = __builtin_amdgcn_cvt_pkrtz(a, b);
  return __builtin_bit_cast(uint32_t, p);
}
// Packed lo-residual for the x-state split (used in B1 only).
__device__ __forceinline__ uint32_t mix_lo_pk(uint32_t hi_pk, float neg1,
                                              float r0, float r1) {
  uint32_t d;
  asm("v_fma_mixlo_f16 %0, %1, %2, %3 op_sel:[0,0,0] op_sel_hi:[1,0,0]\n\t"
      "v_fma_mixhi_f16 %0, %1, %2, %4 op_sel:[1,0,0] op_sel_hi:[1,0,0]"
      : "=&v"(d)
      : "v"(hi_pk), "v"(neg1), "v"(r0), "v"(r1));
  return d;
}

// One-time prep: fragment-layout f16 weight images + folded couple constants.
// Per block i (img 0..13, 512 f16 each):
//   img 0..3   A1[t]   (K: 0-3 W1hi, 4-7 W1lo, 8-11 W1hi, 12/13 b1 hi/lo)
//   img 4..11  A2[t*2+s]  (W2 plain RNE f16 — lo term dropped, R12 evidence:
//     2^-12-scale injection is invisible at the f32 floor)
//   img 12,13  A3[s]  (W3 RNE f16, rows pre-scaled AND replicated into every
//     4-row group so every lane gets a0..a3 in d3; error x0.1-attenuated)
// img 14: couple constants (cwp): per block i, 24 floats:
//   [0..15] Wp'=Wp*diag(sc), [16..19] pb=Wp*go, [20..23] b3 pre-scaled;
//   cwp[192] = grand sum of log(scale).
__global__ void prep_weights(const float* __restrict__ W1, const float* __restrict__ b1,
                             const float* __restrict__ W2, const float* __restrict__ W3,
                             const float* __restrict__ b3, const float* __restrict__ w_perm,
                             const float* __restrict__ g_scale, const float* __restrict__ g_offset,
                             f16* __restrict__ wsp, float* __restrict__ cwp) {
  int i = blockIdx.x / (NIMG + 1);
  int img = blockIdx.x % (NIMG + 1);
  if (img == NIMG) {
    int tid = threadIdx.x;
    if (tid < 16) {
      int cc = tid & 3;
      float gs = g_scale[i * 4 + cc];
      float sc = 0.2f * log1pf(expf(0.5f * gs));
      cwp[i * 24 + tid] = w_perm[i * 16 + tid] * sc;
    } else if (tid < 20) {
      int r = tid - 16;
      float acc = 0.f;
      for (int cc = 0; cc < 4; ++cc)
        acc += w_perm[i * 16 + r * 4 + cc] * g_offset[i * 4 + cc];
      cwp[i * 24 + 16 + r] = acc;
    } else if (tid < 24) {
      int j = tid - 20;
      float scale = (j < 2) ? (0.2f * LOG2E) : 0.1f;
      cwp[i * 24 + 20 + j] = b3[i * 4 + j] * scale;
    } else if (tid == 24 && i == 0) {
      float acc = 0.f;
      for (int k = 0; k < 32; ++k)
        acc += logf(0.2f * log1pf(expf(0.5f * g_scale[k])));
      cwp[192] = acc;
    }
    return;
  }
  int lane = threadIdx.x;
  int c = lane & 15, g = lane >> 4;
  f16 vals[8];
#pragma unroll
  for (int e = 0; e < 8; ++e) {
    float out = 0.f;
    if (img < 4) {
      int t = img, m = 16 * t + c, k = 8 * g + e;
      if (k < 4)        out = hi_part(W1[i * 256 + m * 4 + k]);
      else if (k < 8)   out = lo_part(W1[i * 256 + m * 4 + (k - 4)]);
      else if (k < 12)  out = hi_part(W1[i * 256 + m * 4 + (k - 8)]);
      else if (k == 12) out = hi_part(b1[i * 64 + m]);
      else if (k == 13) out = lo_part(b1[i * 64 + m]);
      else out = 0.f;
    } else if (img < 12) {
      int q = img - 4;
      int t = q >> 1, s = q & 1, m = 16 * t + c;
      int k = 32 * s + 8 * g + e;
      out = hi_part(W2[i * 4096 + m * 64 + pinv(k)]);  // plain RNE f16
    } else {
      int s = img - 12;
      int k = 32 * s + 8 * g + e;
      int rr = c & 3;  // replicate W3 rows into every 4-row group
      float rs = (rr < 2) ? (0.2f * LOG2E) : 0.1f;  // fold 0.1 and 2*log2e
      out = hi_part(W3[i * 256 + rr * 64 + pinv(k)] * rs);
    }
    vals[e] = (f16)out;
  }
  f16x8 vv = {vals[0], vals[1], vals[2], vals[3], vals[4], vals[5], vals[6], vals[7]};
  *(f16x8*)(wsp + ((size_t)i * NIMG + img) * 512 + (size_t)lane * 8) = vv;
}

// Two D tiles -> packed RTZ f16 conversion + packed relu: 8 VALU ops total.
// relu-after-convert == convert-after-relu for these values.
__device__ __forceinline__ f16x8 make_bh(const f32x4 d0, const f32x4 d1,
                                         uint32_t zero_u) {
  u32x4 u;
  u[0] = pkrtz_u(d0[0], d0[1]);
  u[1] = pkrtz_u(d0[2], d0[3]);
  u[2] = pkrtz_u(d1[0], d1[1]);
  u[3] = pkrtz_u(d1[2], d1[3]);
#pragma unroll
  for (int p = 0; p < 4; ++p) {
    uint32_t r;
    asm("v_pk_max_f16 %0, %1, %2" : "=v"(r) : "v"(u[p]), "v"(zero_u));
    u[p] = r;
  }
  return __builtin_bit_cast(f16x8, u);
}

struct Pt {
  float x0, x1, x2, x3, ld;
  uint32_t ch_pk, cl_pk;
};

__device__ __forceinline__ f16x8 build_B1(const Pt& s, bool g0, bool g1, float neg1) {
  const uint32_t ones_pk = 0x3C003C00u;  // packed f16 {1,1}
  uint32_t xh_pk = pkrtz_u(s.x0, s.x1);
  uint32_t xl_pk = mix_lo_pk(xh_pk, neg1, s.x0, s.x1);
  u32x4 B1u = {g0 ? xh_pk : (g1 ? xl_pk : 0u),
               g0 ? s.ch_pk : (g1 ? s.cl_pk : 0u),
               g0 ? xh_pk : (g1 ? ones_pk : 0u),
               g0 ? s.ch_pk : 0u};
  return __builtin_bit_cast(f16x8, B1u);
}

// d3 regs (ALL lanes, via W3 row-replication): 0,1 = 2a*log2e ; 2,3 = t.
__device__ __forceinline__ void couple(Pt& st, const f32x4 d3,
                                       const float* __restrict__ cw) {
  float a0 = d3[0] + cw[20];
  float a1 = d3[1] + cw[21];
  float t2 = d3[2] + cw[22];
  float t3 = d3[3] + cw[23];
  float u0 = fast_exp2(a0), u1 = fast_exp2(a1);          // e^{2a}
  float s0 = fmaf(-4.f, fast_rcp(u0 + 1.f), 2.f);        // 2*tanh(a)
  float s1 = fmaf(-4.f, fast_rcp(u1 + 1.f), 2.f);
  float e0 = fast_exp2(s0 * LOG2E), e1 = fast_exp2(s1 * LOG2E);
  st.x2 = fmaf(st.x2, e0, t2);
  st.x3 = fmaf(st.x3, e1, t3);
  st.ld += s0 + s1;
  // fused actnorm+permutation: nx_r = pb[r] + sum_c Wp'[r][c]*x_c
  float nx0 = fmaf(st.x0, cw[0],  fmaf(st.x1, cw[1],  fmaf(st.x2, cw[2],  fmaf(st.x3, cw[3],  cw[16]))));
  float nx1 = fmaf(st.x0, cw[4],  fmaf(st.x1, cw[5],  fmaf(st.x2, cw[6],  fmaf(st.x3, cw[7],  cw[17]))));
  float nx2 = fmaf(st.x0, cw[8],  fmaf(st.x1, cw[9],  fmaf(st.x2, cw[10], fmaf(st.x3, cw[11], cw[18]))));
  float nx3 = fmaf(st.x0, cw[12], fmaf(st.x1, cw[13], fmaf(st.x2, cw[14], fmaf(st.x3, cw[15], cw[19]))));
  st.x0 = nx0; st.x1 = nx1; st.x2 = nx2; st.x3 = nx3;
}

// Triple-stream, f16 activations, W1 split (free K-slots), W2/W3 plain f16.
// 42 MFMAs/iter (was 72): L2 = 2 MFMAs per output tile, L3 = 2 total.
__global__ __launch_bounds__(256) void cinn_mfma_kernel(
    const float* __restrict__ q_feat, const float* __restrict__ Hc,
    const float* __restrict__ b2, const f16* __restrict__ wf,
    const float* __restrict__ cwp,
    float* __restrict__ out_x, float* __restrict__ out_ld, int n) {
  int lane = threadIdx.x & 63;
  int c = lane & 15, g = lane >> 4;
  bool g0 = (g == 0), g1 = (g == 1);
  int wave = (blockIdx.x * blockDim.x + threadIdx.x) >> 6;
  float neg1 = -1.0f;
  uint32_t zero_u = 0u;

  int pt[NS];
  Pt st[NS];
#pragma unroll
  for (int u = 0; u < NS; ++u) {
    int p = wave * (16 * NS) + u * 16 + c;
    if (p >= n) p = n - 1;  // clamped lanes compute identical results (benign)
    pt[u] = p;
    float4 xv = *reinterpret_cast<const float4*>(q_feat + (size_t)p * 4);
    st[u].x0 = xv.x; st[u].x1 = xv.y; st[u].x2 = xv.z; st[u].x3 = xv.w;
    st[u].ld = 0.f;
    float2 hv = *reinterpret_cast<const float2*>(Hc + (size_t)p * 2);
    st[u].ch_pk = pkrtz_u(hv.x, hv.y);
    st[u].cl_pk = mix_lo_pk(st[u].ch_pk, neg1, hv.x, hv.y);
  }

  const f32x4 zero4 = {0.f, 0.f, 0.f, 0.f};

#pragma unroll 1
  for (int i = 0; i < NBLK; ++i) {
    const f16* wb = wf + (size_t)i * NIMG * 512 + (size_t)lane * 8;
    const float* cw = cwp + i * 24;

    f16x8 B1[NS];
#pragma unroll
    for (int u = 0; u < NS; ++u) B1[u] = build_B1(st[u], g0, g1, neg1);

    // L1 (split terms + b1 folded into K-slots)
    f16x8 b2h[NS][2];
#pragma unroll
    for (int half = 0; half < 2; ++half) {
      f32x4 dp[NS][2];
#pragma unroll
      for (int tt = 0; tt < 2; ++tt) {
        f16x8 a = *(const f16x8*)(wb + (2 * half + tt) * 512);
#pragma unroll
        for (int u = 0; u < NS; ++u) dp[u][tt] = MFMA(a, B1[u], zero4);
      }
#pragma unroll
      for (int u = 0; u < NS; ++u)
        b2h[u][half] = make_bh(dp[u][0], dp[u][1], zero_u);
    }

    // L2: W2 * h over 2 K-halves; b2 bias enters as MFMA C-input
    f16x8 b3h[NS][2];
#pragma unroll
    for (int half = 0; half < 2; ++half) {
      f32x4 d2[NS][2];
#pragma unroll
      for (int tt = 0; tt < 2; ++tt) {
        int t = 2 * half + tt;
        f16x8 ah0 = *(const f16x8*)(wb + (4 + 2 * t + 0) * 512);
        f16x8 ah1 = *(const f16x8*)(wb + (4 + 2 * t + 1) * 512);
        const float4 bv = *reinterpret_cast<const float4*>(b2 + i * 64 + 16 * t + 4 * g);
        f32x4 cin = {bv.x, bv.y, bv.z, bv.w};
#pragma unroll
        for (int u = 0; u < NS; ++u) {
          f32x4 acc = MFMA(ah0, b2h[u][0], cin);
          acc = MFMA(ah1, b2h[u][1], acc);
          d2[u][tt] = acc;
        }
      }
#pragma unroll
      for (int u = 0; u < NS; ++u)
        b3h[u][half] = make_bh(d2[u][0], d2[u][1], zero_u);
    }

    // L3: W3 * h2 (rows replicated -> every lane gets a0..a3)
    f32x4 d3[NS];
    {
      f16x8 ah0 = *(const f16x8*)(wb + 12 * 512);
      f16x8 ah1 = *(const f16x8*)(wb + 13 * 512);
#pragma unroll
      for (int u = 0; u < NS; ++u) {
        f32x4 acc = MFMA(ah0, b3h[u][0], zero4);
        acc = MFMA(ah1, b3h[u][1], acc);
        d3[u] = acc;
      }
    }

#pragma unroll
    for (int u = 0; u < NS; ++u) couple(st[u], d3[u], cw);
  }

  if (lane < 16) {
    float lt = cwp[192];
#pragma unroll
    for (int u = 0; u < NS; ++u) {
      *reinterpret_cast<float4*>(out_x + (size_t)pt[u] * 4) =
          make_float4(st[u].x0, st[u].x1, st[u].x2, st[u].x3);
      out_ld[pt[u]] = st[u].ld + lt;
    }
  }
}

extern "C" void kernel_launch(void* const* d_in, const int* in_sizes, int n_in,
                              void* d_out, int out_size, void* d_ws, size_t ws_size,
                              hipStream_t stream) {
  const float* q_feat   = (const float*)d_in[0];
  const float* Hc       = (const float*)d_in[1];
  const float* W1       = (const float*)d_in[2];
  const float* b1       = (const float*)d_in[3];
  const float* W2       = (const float*)d_in[4];
  const float* b2       = (const float*)d_in[5];
  const float* W3       = (const float*)d_in[6];
  const float* b3       = (const float*)d_in[7];
  const float* w_perm   = (const float*)d_in[8];
  const float* g_scale  = (const float*)d_in[9];
  const float* g_offset = (const float*)d_in[10];

  int n = in_sizes[0] / 4;
  float* out_x  = (float*)d_out;
  float* out_ld = out_x + (size_t)n * 4;
  f16* wf = (f16*)d_ws;                          // 8*14*512*2 = 114688 B
  float* cwp = (float*)((char*)d_ws + 114688);   // 193 floats

  hipLaunchKernelGGL(prep_weights, dim3(NBLK * (NIMG + 1)), dim3(64), 0, stream,
                     W1, b1, W2, W3, b3, w_perm, g_scale, g_offset, wf, cwp);
  int ppb = 256 / 64 * 16 * NS;  // points per 256-thread block = 192
  int blocks = (n + ppb - 1) / ppb;
  hipLaunchKernelGGL(cinn_mfma_kernel, dim3(blocks), dim3(256), 0, stream,
                     q_feat, Hc, b2, wf, cwp, out_x, out_ld, n);
}